// Round 6
// baseline (671.864 us; speedup 1.0000x reference)
//
#include <hip/hip_runtime.h>
#include <hip/hip_bf16.h>

#define N_NODES 100000
#define N_EDGES 3200000
#define N_GRAPHS 64
#define NB 391                 // dst-buckets of 256 nodes (last has 160)
#define KCH 8192               // edges per binning block
#define NCHUNK ((N_EDGES + KCH - 1) / KCH)   // 391
#define MAXBKT 10240           // passB staging capacity (mean 8192, sigma ~90)

__device__ __forceinline__ void atomAddF(float* p, float v) {
    unsafeAtomicAdd(p, v);
}

// bf16x2 pack/unpack (RTNE via __float2bfloat16)
__device__ __forceinline__ float lo2f(unsigned u) { return __uint_as_float(u << 16); }
__device__ __forceinline__ float hi2f(unsigned u) { return __uint_as_float(u & 0xFFFF0000u); }
__device__ __forceinline__ unsigned pack2(float a, float b) {
    unsigned ha = __bfloat16_as_ushort(__float2bfloat16(a));
    unsigned hb = __bfloat16_as_ushort(__float2bfloat16(b));
    return ha | (hb << 16);
}

// ---------------- CSR build: two-level binning ----------------
__global__ __launch_bounds__(512) void k_binCount(const int* __restrict__ dst,
                                                  int* __restrict__ gcount) {
    __shared__ int hist[NB];
    for (int t = threadIdx.x; t < NB; t += 512) hist[t] = 0;
    __syncthreads();
    int base = blockIdx.x * KCH;
    int cnt = min(KCH, N_EDGES - base);
    for (int i = threadIdx.x; i < cnt; i += 512)
        atomicAdd(&hist[dst[base + i] >> 8], 1);
    __syncthreads();
    for (int t = threadIdx.x; t < NB; t += 512)
        if (hist[t]) atomicAdd(&gcount[t], hist[t]);
}

__global__ __launch_bounds__(512) void k_scanB(const int* __restrict__ gcount,
                                               int* __restrict__ gbase,
                                               int* __restrict__ gcursor,
                                               int* __restrict__ rowptr) {
    __shared__ int s[512];
    int v = (threadIdx.x < NB) ? gcount[threadIdx.x] : 0;
    s[threadIdx.x] = v;
    __syncthreads();
    for (int off = 1; off < 512; off <<= 1) {
        int t = (threadIdx.x >= off) ? s[threadIdx.x - off] : 0;
        __syncthreads();
        s[threadIdx.x] += t;
        __syncthreads();
    }
    if (threadIdx.x < NB) {
        int e = s[threadIdx.x] - v;
        gbase[threadIdx.x] = e;
        gcursor[threadIdx.x] = e;
    }
    if (threadIdx.x == 0) rowptr[N_NODES] = N_EDGES;
}

__global__ __launch_bounds__(512) void k_binA(const int* __restrict__ src,
                                              const int* __restrict__ dst,
                                              int* __restrict__ gcursor,
                                              int* __restrict__ binned) {
    __shared__ int hist[512];
    __shared__ int sc[512];
    __shared__ int sexc[512];
    __shared__ int rbase[512];
    __shared__ int stage[KCH];      // 32 KB
    hist[threadIdx.x] = 0;
    __syncthreads();
    int base = blockIdx.x * KCH;
    int cnt = min(KCH, N_EDGES - base);
    int myb[16], mypos[16];
    int nmine = 0;
    for (int i = 0; i < 16; ++i) {
        int idx = i * 512 + threadIdx.x;
        if (idx < cnt) {
            int b = dst[base + idx] >> 8;
            myb[nmine] = b;
            mypos[nmine] = atomicAdd(&hist[b], 1);
            ++nmine;
        }
    }
    __syncthreads();
    int v = hist[threadIdx.x];
    sc[threadIdx.x] = v;
    __syncthreads();
    for (int off = 1; off < 512; off <<= 1) {
        int t = (threadIdx.x >= off) ? sc[threadIdx.x - off] : 0;
        __syncthreads();
        sc[threadIdx.x] += t;
        __syncthreads();
    }
    sexc[threadIdx.x] = sc[threadIdx.x] - v;
    __syncthreads();
    if (threadIdx.x < NB && v > 0)
        rbase[threadIdx.x] = atomicAdd(&gcursor[threadIdx.x], v);
    for (int k = 0; k < nmine; ++k) {
        int e = base + k * 512 + threadIdx.x;
        int p = ((dst[e] & 255) << 24) | src[e];
        stage[sexc[myb[k]] + mypos[k]] = p;
    }
    __syncthreads();
    for (int j = threadIdx.x; j < cnt; j += 512) {
        int lo = 0, hi = NB - 1;
        while (lo < hi) {
            int mid = (lo + hi + 1) >> 1;
            if (sexc[mid] <= j) lo = mid; else hi = mid - 1;
        }
        binned[rbase[lo] + (j - sexc[lo])] = stage[j];
    }
}

__global__ __launch_bounds__(512) void k_passB(const int* __restrict__ gbase,
                                               int* __restrict__ csr,
                                               int* __restrict__ rowptr,
                                               float* __restrict__ dinv) {
    int b = blockIdx.x;
    int rb = gbase[b];
    int re = (b == NB - 1) ? N_EDGES : gbase[b + 1];
    int cnt = re - rb;
    int nbase = b << 8;
    int nn = min(nbase + 256, N_NODES) - nbase;
    __shared__ int stage[MAXBKT];   // 40 KB
    __shared__ int nhist[256];
    __shared__ int sc[256];
    __shared__ int ncur[256];
    for (int t = threadIdx.x; t < 256; t += 512) nhist[t] = 0;
    __syncthreads();
    for (int j = threadIdx.x; j < cnt; j += 512) {
        int p = csr[rb + j];
        stage[j] = p;
        atomicAdd(&nhist[((unsigned)p) >> 24], 1);
    }
    __syncthreads();
    if (threadIdx.x < 256) sc[threadIdx.x] = nhist[threadIdx.x];
    __syncthreads();
    for (int off = 1; off < 256; off <<= 1) {
        int t = (threadIdx.x < 256 && threadIdx.x >= off) ? sc[threadIdx.x - off] : 0;
        __syncthreads();
        if (threadIdx.x < 256) sc[threadIdx.x] += t;
        __syncthreads();
    }
    if (threadIdx.x < 256) {
        int e = sc[threadIdx.x] - nhist[threadIdx.x];
        ncur[threadIdx.x] = e;
        if (threadIdx.x < nn) {
            rowptr[nbase + threadIdx.x] = rb + e;
            dinv[nbase + threadIdx.x] = rsqrtf((float)nhist[threadIdx.x] + 1.0f);
        }
    }
    __syncthreads();
    for (int j = threadIdx.x; j < cnt; j += 512) {
        int p = stage[j];
        int slot = atomicAdd(&ncur[((unsigned)p) >> 24], 1);
        csr[rb + slot] = p;
    }
}

// -------- gather propagation: out = Ahat * in (+bias, relu); bf16 in --------
// W/4 lanes per node; each lane handles 4 bf16 features (one uint2).
template<int LOGW, bool BIAS_RELU, bool OB>
__global__ void __launch_bounds__(256) k_gatherB(
        const int* __restrict__ rowptr, const int* __restrict__ csr,
        const unsigned* __restrict__ in /* bf16x2 pairs */,
        const float* __restrict__ dinv,
        const float* __restrict__ ba, const float* __restrict__ bb,
        void* __restrict__ out) {
    constexpr int W4 = (1 << LOGW) / 4;   // lanes per node
    constexpr int NPB = 256 / W4;
    int n = blockIdx.x * NPB + (threadIdx.x / W4);
    int sub = threadIdx.x % W4;
    const uint2* in2 = (const uint2*)in;
    float di = dinv[n];
    float selfc = di * di;
    uint2 u = in2[(size_t)n * W4 + sub];
    float4 acc = make_float4(lo2f(u.x) * selfc, hi2f(u.x) * selfc,
                             lo2f(u.y) * selfc, hi2f(u.y) * selfc);
    int j = rowptr[n], end = rowptr[n + 1];
    for (; j < end; ++j) {
        int s = csr[j] & 0xFFFFFF;
        float c = dinv[s] * di;
        uint2 v = in2[(size_t)s * W4 + sub];
        acc.x = fmaf(lo2f(v.x), c, acc.x);
        acc.y = fmaf(hi2f(v.x), c, acc.y);
        acc.z = fmaf(lo2f(v.y), c, acc.z);
        acc.w = fmaf(hi2f(v.y), c, acc.w);
    }
    if (BIAS_RELU) {
        constexpr int H = (1 << LOGW) / 2;
        int d = sub * 4;
        const float* bp = (d < H) ? (ba + d) : (bb + d - H);
        acc.x = fmaxf(acc.x + bp[0], 0.0f);
        acc.y = fmaxf(acc.y + bp[1], 0.0f);
        acc.z = fmaxf(acc.z + bp[2], 0.0f);
        acc.w = fmaxf(acc.w + bp[3], 0.0f);
    }
    if (OB) {
        ((uint2*)out)[(size_t)n * W4 + sub] =
            make_uint2(pack2(acc.x, acc.y), pack2(acc.z, acc.w));
    } else {
        ((float4*)out)[(size_t)n * W4 + sub] = acc;
    }
}

// ------- dense: two-branch matmul, 4 outputs/thread; f32 in, f32/bf16 out -------
template<int IN_W, int OUT_HALF, int A_OFF, int A_W, int B_OFF, bool BR, bool OB>
__global__ void k_dense4(const float* __restrict__ in,
                         const float* __restrict__ Wa, const float* __restrict__ ba,
                         const float* __restrict__ Wb, const float* __restrict__ bb,
                         void* __restrict__ out) {
    __shared__ float sWa[A_W * OUT_HALF];
    __shared__ float sWb[A_W * OUT_HALF];
    __shared__ float sba[OUT_HALF];
    __shared__ float sbb[OUT_HALF];
    for (int t = threadIdx.x; t < A_W * OUT_HALF; t += 256) {
        sWa[t] = Wa[t];
        sWb[t] = Wb[t];
    }
    if (BR && threadIdx.x < OUT_HALF) {
        sba[threadIdx.x] = ba[threadIdx.x];
        sbb[threadIdx.x] = bb[threadIdx.x];
    }
    __syncthreads();
    constexpr int TPN = OUT_HALF / 2;            // threads per node
    int idx = blockIdx.x * 256 + threadIdx.x;    // exact grid: N*TPN
    int n = idx / TPN;
    int q = idx % TPN;
    bool isB = (q * 4) >= OUT_HALF;
    int dd = q * 4 - (isB ? OUT_HALF : 0);
    const float* sW = isB ? sWb : sWa;
    int ko = isB ? B_OFF : A_OFF;
    float4 acc;
    if (BR) {
        const float* bp = isB ? (sbb + dd) : (sba + dd);
        acc = make_float4(bp[0], bp[1], bp[2], bp[3]);
    } else {
        acc = make_float4(0.f, 0.f, 0.f, 0.f);
    }
    const float* row = in + (size_t)n * IN_W + ko;
    #pragma unroll
    for (int k = 0; k < A_W; ++k) {
        float r = row[k];
        float4 wv = *(const float4*)&sW[k * OUT_HALF + dd];
        acc.x = fmaf(r, wv.x, acc.x);
        acc.y = fmaf(r, wv.y, acc.y);
        acc.z = fmaf(r, wv.z, acc.z);
        acc.w = fmaf(r, wv.w, acc.w);
    }
    if (BR) {
        acc.x = fmaxf(acc.x, 0.f); acc.y = fmaxf(acc.y, 0.f);
        acc.z = fmaxf(acc.z, 0.f); acc.w = fmaxf(acc.w, 0.f);
    }
    if (OB) {
        ((uint2*)out)[idx] = make_uint2(pack2(acc.x, acc.y), pack2(acc.z, acc.w));
    } else {
        ((float4*)out)[idx] = acc;
    }
}

// ---------------- pooling (segment reduce; batch is sorted) ----------------
__global__ void k_pool2(const float* __restrict__ h3, const int* __restrict__ batch,
                        float* __restrict__ pool, int* __restrict__ cnt) {
    int g = blockIdx.x >> 2;
    int q = blockIdx.x & 3;
    __shared__ int sb[2];
    if (threadIdx.x < 2) {
        int target = g + threadIdx.x;
        int lo = 0, hi = N_NODES;
        while (lo < hi) {
            int mid = (lo + hi) >> 1;
            if (batch[mid] < target) lo = mid + 1; else hi = mid;
        }
        sb[threadIdx.x] = lo;
    }
    __syncthreads();
    int start = sb[0], end = sb[1];
    int d = threadIdx.x & 127;
    int half = threadIdx.x >> 7;
    float acc = 0.0f;
    for (int n = start + q * 2 + half; n < end; n += 8)
        acc += h3[(size_t)n * 128 + d];
    __shared__ float sred[256];
    sred[threadIdx.x] = acc;
    __syncthreads();
    if (half == 0)
        atomAddF(&pool[g * 128 + d], sred[threadIdx.x] + sred[threadIdx.x + 128]);
    if (threadIdx.x == 0 && q == 0) cnt[g] = end - start;
}

__global__ void k_final(const float* __restrict__ pool, const int* __restrict__ cnt,
                        const float* __restrict__ eps, float* __restrict__ zbuf,
                        float* __restrict__ out_mu, float* __restrict__ out_lv) {
    int idx = blockIdx.x * 256 + threadIdx.x;
    int g = idx >> 6;
    float c = fmaxf((float)cnt[g], 1.0f);
    float mu = pool[g * 128 + (idx & 63)] / c;
    float lv = pool[g * 128 + 64 + (idx & 63)] / c;
    zbuf[idx] = mu + eps[idx] * __expf(0.5f * lv);
    out_mu[idx] = mu;
    out_lv[idx] = lv;
}

// ---------------- decode: sigmoid(z @ Wfc + bfc) ----------------
__global__ void __launch_bounds__(256) k_decode(const float* __restrict__ zbuf,
                                                const float* __restrict__ Wfc,
                                                const float* __restrict__ bfc,
                                                float* __restrict__ out) {
    __shared__ float sz[64 * 64];
    for (int t = threadIdx.x; t < 4096; t += 256) sz[t] = zbuf[t];
    __syncthreads();
    int j = blockIdx.x * 256 + threadIdx.x;
    float bias = bfc[j];
    float acc[64];
    #pragma unroll
    for (int g = 0; g < 64; ++g) acc[g] = bias;
    #pragma unroll 4
    for (int k4 = 0; k4 < 16; ++k4) {
        float w0 = Wfc[(k4 * 4 + 0) * 160000 + j];
        float w1 = Wfc[(k4 * 4 + 1) * 160000 + j];
        float w2 = Wfc[(k4 * 4 + 2) * 160000 + j];
        float w3 = Wfc[(k4 * 4 + 3) * 160000 + j];
        #pragma unroll
        for (int g = 0; g < 64; ++g) {
            float4 zv = *(const float4*)&sz[g * 64 + k4 * 4];
            acc[g] = fmaf(zv.x, w0, acc[g]);
            acc[g] = fmaf(zv.y, w1, acc[g]);
            acc[g] = fmaf(zv.z, w2, acc[g]);
            acc[g] = fmaf(zv.w, w3, acc[g]);
        }
    }
    #pragma unroll
    for (int g = 0; g < 64; ++g) {
        float s = 1.0f / (1.0f + __expf(-acc[g]));
        out[g * 160000 + j] = s;
    }
}

extern "C" void kernel_launch(void* const* d_in, const int* in_sizes, int n_in,
                              void* d_out, int out_size, void* d_ws, size_t ws_size,
                              hipStream_t stream) {
    const float* x     = (const float*)d_in[0];
    const int*   ei    = (const int*)d_in[1];
    const int*   batch = (const int*)d_in[2];
    const float *W1m = (const float*)d_in[3],  *b1m = (const float*)d_in[4];
    const float *W2m = (const float*)d_in[5],  *b2m = (const float*)d_in[6];
    const float *W3m = (const float*)d_in[7],  *b3m = (const float*)d_in[8];
    const float *W1l = (const float*)d_in[9],  *b1l = (const float*)d_in[10];
    const float *W2l = (const float*)d_in[11], *b2l = (const float*)d_in[12];
    const float *W3l = (const float*)d_in[13], *b3l = (const float*)d_in[14];
    const float *Wfc = (const float*)d_in[15], *bfc = (const float*)d_in[16];
    const float *eps = (const float*)d_in[17];

    const int* srcv = ei;
    const int* dstv = ei + N_EDGES;

    char* w = (char*)d_ws;
    auto alloc = [&](size_t bytes) -> char* {
        char* p = w;
        w += (bytes + 255) & ~(size_t)255;
        return p;
    };
    int*   gcount = (int*)  alloc((size_t)NB * 4);
    int*   gbase  = (int*)  alloc((size_t)NB * 4);
    int*   gcursor= (int*)  alloc((size_t)NB * 4);
    int*   rowptr = (int*)  alloc((size_t)(N_NODES + 1) * 4);
    float* dinv   = (float*)alloc((size_t)N_NODES * 4);
    float* pool   = (float*)alloc((size_t)N_GRAPHS * 128 * 4);
    int*   cnt    = (int*)  alloc((size_t)N_GRAPHS * 4);
    float* zbuf   = (float*)alloc((size_t)N_GRAPHS * 64 * 4);
    // Arena (76.8 MB): A (N*64 f32) | B (N*64 f32) | csr (N_EDGES int) | spare
    //   A: xW bf16 -> A*h1 f32 -> A*h2 f32 (25.6 MB max)
    //   B: h1 bf16 -> h2 bf16 (12.8 MB max)
    //   h3 f32 (51.2 MB) = B..end, aliasing B+csr+spare (dead at dense3 time)
    float* arena = (float*)alloc((size_t)N_NODES * 192 * 4);
    float* A   = arena;
    float* B   = arena + (size_t)N_NODES * 64;
    int*   csr = (int*)(arena + (size_t)N_NODES * 128);
    float* h3  = B;

    float* out    = (float*)d_out;
    float* out_mu = out + 10240000;
    float* out_lv = out + 10240000 + 4096;

    hipMemsetAsync(gcount, 0, (size_t)NB * 4, stream);
    hipMemsetAsync(pool, 0, (size_t)N_GRAPHS * 128 * 4, stream);

    // ---- CSR build (binned) ----
    k_binCount<<<NCHUNK, 512, 0, stream>>>(dstv, gcount);
    k_scanB<<<1, 512, 0, stream>>>(gcount, gbase, gcursor, rowptr);
    k_binA<<<NCHUNK, 512, 0, stream>>>(srcv, dstv, gcursor, csr);
    k_passB<<<NB, 512, 0, stream>>>(gbase, csr, rowptr, dinv);

    // ---- L1: dense (x @ [W1m|W1l]) -> bf16; gather w32 (+bias+relu) -> bf16 h1 ----
    k_dense4<64, 16, 0, 64, 0, false, true><<<N_NODES * 8 / 256, 256, 0, stream>>>(
        x, W1m, b1m, W1l, b1l, A);
    k_gatherB<5, true, true><<<N_NODES / 32, 256, 0, stream>>>(
        rowptr, csr, (const unsigned*)A, dinv, b1m, b1l, B);

    // ---- L2: gather w32 (bf16 h1) -> f32; dense 16->32 x2 -> bf16 h2 ----
    k_gatherB<5, false, false><<<N_NODES / 32, 256, 0, stream>>>(
        rowptr, csr, (const unsigned*)B, dinv, b1m, b1l, A);
    k_dense4<32, 32, 0, 16, 16, true, true><<<N_NODES * 16 / 256, 256, 0, stream>>>(
        A, W2m, b2m, W2l, b2l, B);

    // ---- L3: gather w64 (bf16 h2) -> f32; dense 32->64 x2 -> f32 h3 ----
    k_gatherB<6, false, false><<<N_NODES / 16, 256, 0, stream>>>(
        rowptr, csr, (const unsigned*)B, dinv, b1m, b1l, A);
    k_dense4<64, 64, 0, 32, 32, true, false><<<N_NODES * 32 / 256, 256, 0, stream>>>(
        A, W3m, b3m, W3l, b3l, h3);

    // ---- mean pool + reparameterize ----
    k_pool2<<<N_GRAPHS * 4, 256, 0, stream>>>(h3, batch, pool, cnt);
    k_final<<<16, 256, 0, stream>>>(pool, cnt, eps, zbuf, out_mu, out_lv);

    // ---- decode ----
    k_decode<<<625, 256, 0, stream>>>(zbuf, Wfc, bfc, out);
}

// Round 7
// 513.681 us; speedup vs baseline: 1.3079x; 1.3079x over previous
//
#include <hip/hip_runtime.h>
#include <hip/hip_bf16.h>

#define N_NODES 100000
#define N_EDGES 3200000
#define N_GRAPHS 64
#define NB 391                 // dst-buckets of 256 nodes (last has 160)
#define KCH 8192               // edges per binning block
#define NCHUNK ((N_EDGES + KCH - 1) / KCH)   // 391
#define MAXBKT 10240           // passB staging capacity (mean 8192, sigma ~90)

__device__ __forceinline__ void atomAddF(float* p, float v) {
    unsafeAtomicAdd(p, v);
}

// bf16x2 pack/unpack (RTNE via __float2bfloat16)
__device__ __forceinline__ float lo2f(unsigned u) { return __uint_as_float(u << 16); }
__device__ __forceinline__ float hi2f(unsigned u) { return __uint_as_float(u & 0xFFFF0000u); }
__device__ __forceinline__ unsigned pack2(float a, float b) {
    unsigned ha = __bfloat16_as_ushort(__float2bfloat16(a));
    unsigned hb = __bfloat16_as_ushort(__float2bfloat16(b));
    return ha | (hb << 16);
}

// ---------------- CSR build: two-level binning ----------------
__global__ __launch_bounds__(512) void k_binCount(const int* __restrict__ dst,
                                                  int* __restrict__ gcount) {
    __shared__ int hist[NB];
    for (int t = threadIdx.x; t < NB; t += 512) hist[t] = 0;
    __syncthreads();
    int base = blockIdx.x * KCH;
    int cnt = min(KCH, N_EDGES - base);
    for (int i = threadIdx.x; i < cnt; i += 512)
        atomicAdd(&hist[dst[base + i] >> 8], 1);
    __syncthreads();
    for (int t = threadIdx.x; t < NB; t += 512)
        if (hist[t]) atomicAdd(&gcount[t], hist[t]);
}

__global__ __launch_bounds__(512) void k_scanB(const int* __restrict__ gcount,
                                               int* __restrict__ gbase,
                                               int* __restrict__ gcursor,
                                               int* __restrict__ rowptr) {
    __shared__ int s[512];
    int v = (threadIdx.x < NB) ? gcount[threadIdx.x] : 0;
    s[threadIdx.x] = v;
    __syncthreads();
    for (int off = 1; off < 512; off <<= 1) {
        int t = (threadIdx.x >= off) ? s[threadIdx.x - off] : 0;
        __syncthreads();
        s[threadIdx.x] += t;
        __syncthreads();
    }
    if (threadIdx.x < NB) {
        int e = s[threadIdx.x] - v;
        gbase[threadIdx.x] = e;
        gcursor[threadIdx.x] = e;
    }
    if (threadIdx.x == 0) rowptr[N_NODES] = N_EDGES;
}

__global__ __launch_bounds__(512) void k_binA(const int* __restrict__ src,
                                              const int* __restrict__ dst,
                                              int* __restrict__ gcursor,
                                              int* __restrict__ binned) {
    __shared__ int hist[512];
    __shared__ int sc[512];
    __shared__ int sexc[512];
    __shared__ int rbase[512];
    __shared__ int stage[KCH];      // 32 KB
    hist[threadIdx.x] = 0;
    __syncthreads();
    int base = blockIdx.x * KCH;
    int cnt = min(KCH, N_EDGES - base);
    int myb[16], mypos[16];
    int nmine = 0;
    for (int i = 0; i < 16; ++i) {
        int idx = i * 512 + threadIdx.x;
        if (idx < cnt) {
            int b = dst[base + idx] >> 8;
            myb[nmine] = b;
            mypos[nmine] = atomicAdd(&hist[b], 1);
            ++nmine;
        }
    }
    __syncthreads();
    int v = hist[threadIdx.x];
    sc[threadIdx.x] = v;
    __syncthreads();
    for (int off = 1; off < 512; off <<= 1) {
        int t = (threadIdx.x >= off) ? sc[threadIdx.x - off] : 0;
        __syncthreads();
        sc[threadIdx.x] += t;
        __syncthreads();
    }
    sexc[threadIdx.x] = sc[threadIdx.x] - v;
    __syncthreads();
    if (threadIdx.x < NB && v > 0)
        rbase[threadIdx.x] = atomicAdd(&gcursor[threadIdx.x], v);
    for (int k = 0; k < nmine; ++k) {
        int e = base + k * 512 + threadIdx.x;
        int p = ((dst[e] & 255) << 24) | src[e];
        stage[sexc[myb[k]] + mypos[k]] = p;
    }
    __syncthreads();
    for (int j = threadIdx.x; j < cnt; j += 512) {
        int lo = 0, hi = NB - 1;
        while (lo < hi) {
            int mid = (lo + hi + 1) >> 1;
            if (sexc[mid] <= j) lo = mid; else hi = mid - 1;
        }
        binned[rbase[lo] + (j - sexc[lo])] = stage[j];
    }
}

__global__ __launch_bounds__(512) void k_passB(const int* __restrict__ gbase,
                                               int* __restrict__ csr,
                                               int* __restrict__ rowptr,
                                               float* __restrict__ dinv) {
    int b = blockIdx.x;
    int rb = gbase[b];
    int re = (b == NB - 1) ? N_EDGES : gbase[b + 1];
    int cnt = re - rb;
    int nbase = b << 8;
    int nn = min(nbase + 256, N_NODES) - nbase;
    __shared__ int stage[MAXBKT];   // 40 KB
    __shared__ int nhist[256];
    __shared__ int sc[256];
    __shared__ int ncur[256];
    for (int t = threadIdx.x; t < 256; t += 512) nhist[t] = 0;
    __syncthreads();
    for (int j = threadIdx.x; j < cnt; j += 512) {
        int p = csr[rb + j];
        stage[j] = p;
        atomicAdd(&nhist[((unsigned)p) >> 24], 1);
    }
    __syncthreads();
    if (threadIdx.x < 256) sc[threadIdx.x] = nhist[threadIdx.x];
    __syncthreads();
    for (int off = 1; off < 256; off <<= 1) {
        int t = (threadIdx.x < 256 && threadIdx.x >= off) ? sc[threadIdx.x - off] : 0;
        __syncthreads();
        if (threadIdx.x < 256) sc[threadIdx.x] += t;
        __syncthreads();
    }
    if (threadIdx.x < 256) {
        int e = sc[threadIdx.x] - nhist[threadIdx.x];
        ncur[threadIdx.x] = e;
        if (threadIdx.x < nn) {
            rowptr[nbase + threadIdx.x] = rb + e;
            dinv[nbase + threadIdx.x] = rsqrtf((float)nhist[threadIdx.x] + 1.0f);
        }
    }
    __syncthreads();
    for (int j = threadIdx.x; j < cnt; j += 512) {
        int p = stage[j];
        int slot = atomicAdd(&ncur[((unsigned)p) >> 24], 1);
        csr[rb + slot] = p;
    }
}

// -------- gather: out = di*(sum A'[s] + A'[n]) (+bias,relu) --------
// Features pre-scaled by dinv (A'[u] = dinv[u]*h[u]) => no per-edge dinv/coef.
// 4-way unrolled edge loop for memory-level parallelism.
template<int LOGW, bool BIAS_RELU, bool OB, bool PRE>
__global__ void __launch_bounds__(256) k_gatherB(
        const int* __restrict__ rowptr, const int* __restrict__ csr,
        const unsigned* __restrict__ in /* bf16x2 pairs, prescaled */,
        const float* __restrict__ dinv,
        const float* __restrict__ ba, const float* __restrict__ bb,
        void* __restrict__ out) {
    constexpr int W4 = (1 << LOGW) / 4;   // lanes per node
    constexpr int NPB = 256 / W4;
    int n = blockIdx.x * NPB + (threadIdx.x / W4);
    int sub = threadIdx.x % W4;
    const uint2* in2 = (const uint2*)in;
    uint2 u = in2[(size_t)n * W4 + sub];              // self term A'[n]
    float4 acc = make_float4(lo2f(u.x), hi2f(u.x), lo2f(u.y), hi2f(u.y));
    int j = rowptr[n], end = rowptr[n + 1];
    for (; j + 4 <= end; j += 4) {
        int s0 = csr[j] & 0xFFFFFF;
        int s1 = csr[j + 1] & 0xFFFFFF;
        int s2 = csr[j + 2] & 0xFFFFFF;
        int s3 = csr[j + 3] & 0xFFFFFF;
        uint2 v0 = in2[(size_t)s0 * W4 + sub];
        uint2 v1 = in2[(size_t)s1 * W4 + sub];
        uint2 v2 = in2[(size_t)s2 * W4 + sub];
        uint2 v3 = in2[(size_t)s3 * W4 + sub];
        acc.x += (lo2f(v0.x) + lo2f(v1.x)) + (lo2f(v2.x) + lo2f(v3.x));
        acc.y += (hi2f(v0.x) + hi2f(v1.x)) + (hi2f(v2.x) + hi2f(v3.x));
        acc.z += (lo2f(v0.y) + lo2f(v1.y)) + (lo2f(v2.y) + lo2f(v3.y));
        acc.w += (hi2f(v0.y) + hi2f(v1.y)) + (hi2f(v2.y) + hi2f(v3.y));
    }
    for (; j < end; ++j) {
        int s = csr[j] & 0xFFFFFF;
        uint2 v = in2[(size_t)s * W4 + sub];
        acc.x += lo2f(v.x);
        acc.y += hi2f(v.x);
        acc.z += lo2f(v.y);
        acc.w += hi2f(v.y);
    }
    float di = dinv[n];
    acc.x *= di; acc.y *= di; acc.z *= di; acc.w *= di;
    if (BIAS_RELU) {
        constexpr int H = (1 << LOGW) / 2;
        int d = sub * 4;
        const float* bp = (d < H) ? (ba + d) : (bb + d - H);
        acc.x = fmaxf(acc.x + bp[0], 0.0f);
        acc.y = fmaxf(acc.y + bp[1], 0.0f);
        acc.z = fmaxf(acc.z + bp[2], 0.0f);
        acc.w = fmaxf(acc.w + bp[3], 0.0f);
    }
    if (PRE) {  // pre-scale for the NEXT gather layer
        acc.x *= di; acc.y *= di; acc.z *= di; acc.w *= di;
    }
    if (OB) {
        ((uint2*)out)[(size_t)n * W4 + sub] =
            make_uint2(pack2(acc.x, acc.y), pack2(acc.z, acc.w));
    } else {
        ((float4*)out)[(size_t)n * W4 + sub] = acc;
    }
}

// ------- dense: two-branch matmul, 4 outputs/thread; optional dinv out-scale -------
template<int IN_W, int OUT_HALF, int A_OFF, int A_W, int B_OFF, bool BR, bool OB, bool DS>
__global__ void k_dense4(const float* __restrict__ in,
                         const float* __restrict__ Wa, const float* __restrict__ ba,
                         const float* __restrict__ Wb, const float* __restrict__ bb,
                         const float* __restrict__ dinv,
                         void* __restrict__ out) {
    __shared__ float sWa[A_W * OUT_HALF];
    __shared__ float sWb[A_W * OUT_HALF];
    __shared__ float sba[OUT_HALF];
    __shared__ float sbb[OUT_HALF];
    for (int t = threadIdx.x; t < A_W * OUT_HALF; t += 256) {
        sWa[t] = Wa[t];
        sWb[t] = Wb[t];
    }
    if (BR && threadIdx.x < OUT_HALF) {
        sba[threadIdx.x] = ba[threadIdx.x];
        sbb[threadIdx.x] = bb[threadIdx.x];
    }
    __syncthreads();
    constexpr int TPN = OUT_HALF / 2;            // threads per node
    int idx = blockIdx.x * 256 + threadIdx.x;    // exact grid: N*TPN
    int n = idx / TPN;
    int q = idx % TPN;
    bool isB = (q * 4) >= OUT_HALF;
    int dd = q * 4 - (isB ? OUT_HALF : 0);
    const float* sW = isB ? sWb : sWa;
    int ko = isB ? B_OFF : A_OFF;
    float4 acc;
    if (BR) {
        const float* bp = isB ? (sbb + dd) : (sba + dd);
        acc = make_float4(bp[0], bp[1], bp[2], bp[3]);
    } else {
        acc = make_float4(0.f, 0.f, 0.f, 0.f);
    }
    const float* row = in + (size_t)n * IN_W + ko;
    #pragma unroll
    for (int k = 0; k < A_W; ++k) {
        float r = row[k];
        float4 wv = *(const float4*)&sW[k * OUT_HALF + dd];
        acc.x = fmaf(r, wv.x, acc.x);
        acc.y = fmaf(r, wv.y, acc.y);
        acc.z = fmaf(r, wv.z, acc.z);
        acc.w = fmaf(r, wv.w, acc.w);
    }
    if (BR) {
        acc.x = fmaxf(acc.x, 0.f); acc.y = fmaxf(acc.y, 0.f);
        acc.z = fmaxf(acc.z, 0.f); acc.w = fmaxf(acc.w, 0.f);
    }
    if (DS) {
        float dn = dinv[n];
        acc.x *= dn; acc.y *= dn; acc.z *= dn; acc.w *= dn;
    }
    if (OB) {
        ((uint2*)out)[idx] = make_uint2(pack2(acc.x, acc.y), pack2(acc.z, acc.w));
    } else {
        ((float4*)out)[idx] = acc;
    }
}

// ---------------- pooling (segment reduce; batch is sorted) ----------------
__global__ void k_pool2(const float* __restrict__ h3, const int* __restrict__ batch,
                        float* __restrict__ pool, int* __restrict__ cnt) {
    int g = blockIdx.x >> 2;
    int q = blockIdx.x & 3;
    __shared__ int sb[2];
    if (threadIdx.x < 2) {
        int target = g + threadIdx.x;
        int lo = 0, hi = N_NODES;
        while (lo < hi) {
            int mid = (lo + hi) >> 1;
            if (batch[mid] < target) lo = mid + 1; else hi = mid;
        }
        sb[threadIdx.x] = lo;
    }
    __syncthreads();
    int start = sb[0], end = sb[1];
    int d = threadIdx.x & 127;
    int half = threadIdx.x >> 7;
    float acc = 0.0f;
    for (int n = start + q * 2 + half; n < end; n += 8)
        acc += h3[(size_t)n * 128 + d];
    __shared__ float sred[256];
    sred[threadIdx.x] = acc;
    __syncthreads();
    if (half == 0)
        atomAddF(&pool[g * 128 + d], sred[threadIdx.x] + sred[threadIdx.x + 128]);
    if (threadIdx.x == 0 && q == 0) cnt[g] = end - start;
}

__global__ void k_final(const float* __restrict__ pool, const int* __restrict__ cnt,
                        const float* __restrict__ eps, float* __restrict__ zbuf,
                        float* __restrict__ out_mu, float* __restrict__ out_lv) {
    int idx = blockIdx.x * 256 + threadIdx.x;
    int g = idx >> 6;
    float c = fmaxf((float)cnt[g], 1.0f);
    float mu = pool[g * 128 + (idx & 63)] / c;
    float lv = pool[g * 128 + 64 + (idx & 63)] / c;
    zbuf[idx] = mu + eps[idx] * __expf(0.5f * lv);
    out_mu[idx] = mu;
    out_lv[idx] = lv;
}

// ---------------- decode: sigmoid(z @ Wfc + bfc) ----------------
__global__ void __launch_bounds__(256) k_decode(const float* __restrict__ zbuf,
                                                const float* __restrict__ Wfc,
                                                const float* __restrict__ bfc,
                                                float* __restrict__ out) {
    __shared__ float sz[64 * 64];
    for (int t = threadIdx.x; t < 4096; t += 256) sz[t] = zbuf[t];
    __syncthreads();
    int j = blockIdx.x * 256 + threadIdx.x;
    float bias = bfc[j];
    float acc[64];
    #pragma unroll
    for (int g = 0; g < 64; ++g) acc[g] = bias;
    #pragma unroll 4
    for (int k4 = 0; k4 < 16; ++k4) {
        float w0 = Wfc[(k4 * 4 + 0) * 160000 + j];
        float w1 = Wfc[(k4 * 4 + 1) * 160000 + j];
        float w2 = Wfc[(k4 * 4 + 2) * 160000 + j];
        float w3 = Wfc[(k4 * 4 + 3) * 160000 + j];
        #pragma unroll
        for (int g = 0; g < 64; ++g) {
            float4 zv = *(const float4*)&sz[g * 64 + k4 * 4];
            acc[g] = fmaf(zv.x, w0, acc[g]);
            acc[g] = fmaf(zv.y, w1, acc[g]);
            acc[g] = fmaf(zv.z, w2, acc[g]);
            acc[g] = fmaf(zv.w, w3, acc[g]);
        }
    }
    #pragma unroll
    for (int g = 0; g < 64; ++g) {
        float s = 1.0f / (1.0f + __expf(-acc[g]));
        out[g * 160000 + j] = s;
    }
}

extern "C" void kernel_launch(void* const* d_in, const int* in_sizes, int n_in,
                              void* d_out, int out_size, void* d_ws, size_t ws_size,
                              hipStream_t stream) {
    const float* x     = (const float*)d_in[0];
    const int*   ei    = (const int*)d_in[1];
    const int*   batch = (const int*)d_in[2];
    const float *W1m = (const float*)d_in[3],  *b1m = (const float*)d_in[4];
    const float *W2m = (const float*)d_in[5],  *b2m = (const float*)d_in[6];
    const float *W3m = (const float*)d_in[7],  *b3m = (const float*)d_in[8];
    const float *W1l = (const float*)d_in[9],  *b1l = (const float*)d_in[10];
    const float *W2l = (const float*)d_in[11], *b2l = (const float*)d_in[12];
    const float *W3l = (const float*)d_in[13], *b3l = (const float*)d_in[14];
    const float *Wfc = (const float*)d_in[15], *bfc = (const float*)d_in[16];
    const float *eps = (const float*)d_in[17];

    const int* srcv = ei;
    const int* dstv = ei + N_EDGES;

    char* w = (char*)d_ws;
    auto alloc = [&](size_t bytes) -> char* {
        char* p = w;
        w += (bytes + 255) & ~(size_t)255;
        return p;
    };
    int*   gcount = (int*)  alloc((size_t)NB * 4);
    int*   gbase  = (int*)  alloc((size_t)NB * 4);
    int*   gcursor= (int*)  alloc((size_t)NB * 4);
    int*   rowptr = (int*)  alloc((size_t)(N_NODES + 1) * 4);
    float* dinv   = (float*)alloc((size_t)N_NODES * 4);
    float* pool   = (float*)alloc((size_t)N_GRAPHS * 128 * 4);
    int*   cnt    = (int*)  alloc((size_t)N_GRAPHS * 4);
    float* zbuf   = (float*)alloc((size_t)N_GRAPHS * 64 * 4);
    // Arena (76.8 MB): A (N*64 f32) | B (N*64 f32) | csr (N_EDGES int) | spare
    //   A: dinv*xW bf16 -> A*h1 f32 -> A*h2 f32 (25.6 MB max)
    //   B: dinv*h1 bf16 -> dinv*h2 bf16 (12.8 MB max)
    //   h3 f32 (51.2 MB) = B..end, aliasing B+csr+spare (dead at dense3 time)
    float* arena = (float*)alloc((size_t)N_NODES * 192 * 4);
    float* A   = arena;
    float* B   = arena + (size_t)N_NODES * 64;
    int*   csr = (int*)(arena + (size_t)N_NODES * 128);
    float* h3  = B;

    float* out    = (float*)d_out;
    float* out_mu = out + 10240000;
    float* out_lv = out + 10240000 + 4096;

    hipMemsetAsync(gcount, 0, (size_t)NB * 4, stream);
    hipMemsetAsync(pool, 0, (size_t)N_GRAPHS * 128 * 4, stream);

    // ---- CSR build (binned) ----
    k_binCount<<<NCHUNK, 512, 0, stream>>>(dstv, gcount);
    k_scanB<<<1, 512, 0, stream>>>(gcount, gbase, gcursor, rowptr);
    k_binA<<<NCHUNK, 512, 0, stream>>>(srcv, dstv, gcursor, csr);
    k_passB<<<NB, 512, 0, stream>>>(gbase, csr, rowptr, dinv);

    // ---- L1: dense -> dinv*xW bf16; gather w32 -> dinv*relu(...) bf16 ----
    k_dense4<64, 16, 0, 64, 0, false, true, true><<<N_NODES * 8 / 256, 256, 0, stream>>>(
        x, W1m, b1m, W1l, b1l, dinv, A);
    k_gatherB<5, true, true, true><<<N_NODES / 32, 256, 0, stream>>>(
        rowptr, csr, (const unsigned*)A, dinv, b1m, b1l, B);

    // ---- L2: gather w32 -> f32 agg; dense 16->32 x2 -> dinv*relu bf16 ----
    k_gatherB<5, false, false, false><<<N_NODES / 32, 256, 0, stream>>>(
        rowptr, csr, (const unsigned*)B, dinv, b1m, b1l, A);
    k_dense4<32, 32, 0, 16, 16, true, true, true><<<N_NODES * 16 / 256, 256, 0, stream>>>(
        A, W2m, b2m, W2l, b2l, dinv, B);

    // ---- L3: gather w64 -> f32 agg; dense 32->64 x2 -> f32 h3 ----
    k_gatherB<6, false, false, false><<<N_NODES / 16, 256, 0, stream>>>(
        rowptr, csr, (const unsigned*)B, dinv, b1m, b1l, A);
    k_dense4<64, 64, 0, 32, 32, true, false, false><<<N_NODES * 32 / 256, 256, 0, stream>>>(
        A, W3m, b3m, W3l, b3l, dinv, h3);

    // ---- mean pool + reparameterize ----
    k_pool2<<<N_GRAPHS * 4, 256, 0, stream>>>(h3, batch, pool, cnt);
    k_final<<<16, 256, 0, stream>>>(pool, cnt, eps, zbuf, out_mu, out_lv);

    // ---- decode ----
    k_decode<<<625, 256, 0, stream>>>(zbuf, Wfc, bfc, out);
}